// Round 12
// baseline (280.224 us; speedup 1.0000x reference)
//
#include <hip/hip_runtime.h>
#include <hip/hip_bf16.h>

#define M_TOTAL 16384
#define KDIM 2048
#define NDIM 2048
#define NEXP 8
#define BM 128
#define BN 128
#define BK 32
#define RT_MAX 135          // 16384/128 + 7 boundary extras
#define CT 16               // 2048/128 col tiles
#define NWG (RT_MAX * CT)   // 2160 = 8 * 270
#define BUFB 16384          // (128+128) rows x 64B per K-tile buffer

typedef __attribute__((ext_vector_type(8))) __bf16 bf16x8;
typedef __attribute__((ext_vector_type(4))) float f32x4;

__device__ inline int minI(int a, int b) { return a < b ? a : b; }

__device__ inline bf16x8 cvt8(float4 a, float4 b) {
  bf16x8 r;
  r[0] = (__bf16)a.x; r[1] = (__bf16)a.y; r[2] = (__bf16)a.z; r[3] = (__bf16)a.w;
  r[4] = (__bf16)b.x; r[5] = (__bf16)b.y; r[6] = (__bf16)b.z; r[7] = (__bf16)b.w;
  return r;
}

__device__ inline void gload16(const void* g, void* l) {
  __builtin_amdgcn_global_load_lds(
      (const __attribute__((address_space(1))) void*)g,
      (__attribute__((address_space(3))) void*)l, 16, 0, 0);
}

// ---------------- fp32 -> bf16 conversion (x then W) ----------------
__global__ __launch_bounds__(256) void cvt_both(
    const float* __restrict__ x, const float* __restrict__ w,
    bf16x8* __restrict__ xb, bf16x8* __restrict__ wb) {
  const int NX = (M_TOTAL * KDIM) / 8;
  const int NW = (NEXP * NDIM * KDIM) / 8;
  const int stride = gridDim.x * blockDim.x;
  for (int i = blockIdx.x * blockDim.x + threadIdx.x; i < NX + NW; i += stride) {
    const float4* src = (i < NX) ? ((const float4*)x + (size_t)i * 2)
                                 : ((const float4*)w + (size_t)(i - NX) * 2);
    float4 a = src[0], b = src[1];
    bf16x8 c = cvt8(a, b);
    if (i < NX) xb[i] = c; else wb[i - NX] = c;
  }
}

// ---------------- grouped GEMM: 128x128 tile, BK=32, 3 LDS buffers (48 KB),
// 4 waves (2x2) of 64x64, VGPR<=128 -> THREE BLOCKS CO-RESIDENT PER CU.
// Diagnosis R4-R11: nine schedule variants all pinned at 29-35% MfmaUtil --
// with 1 block/CU (>=96KB LDS) the block's barrier phase-locks all waves, so
// LDS-read windows and MFMA windows alternate with nothing to fill the idle
// pipe. m97's 874 TF came from ~3 blocks/CU implicit overlap (m114). This
// kernel restores that regime: 3 independent barrier domains per CU -- while
// one block reads LDS, another MFMAs, regardless of any in-block serializer.
// Tail also improves: 2160 blocks / 768 slots = 2.8 rounds -> 94% (vs 74%).
// Free-run tile loop (R10 hazard logic, clobber-free counted vmcnt):
//  RAW: vmcnt(4)+barrier(t) retire tile t's 4 units, publish buf(t).
//  WAR: stage(t+2)->buf((t+2)%3): its readers (tile t-1) drained before their
//       MFMAs issued, hence before any wave passed barrier(t).
// Swizzle (verified 0-conflict): phys chunk = c ^ ((row>>1)&3), applied via
// pre-swizzled per-lane global source column; LDS dest stays linear.
__global__ __launch_bounds__(256, 4) void moe_gemm_cr(
    const __hip_bfloat16* __restrict__ xb, const __hip_bfloat16* __restrict__ wb,
    const int* __restrict__ ms, float* __restrict__ out) {
  __shared__ __align__(16) char lds[3 * BUFB];

  // bijective XCD swizzle (NWG = 2160 = 8*270)
  const int orig = blockIdx.x;
  const int wg = (orig & 7) * (NWG / 8) + (orig >> 3);
  const int bt = wg >> 4;     // row-tile 0..134
  const int ntile = wg & 15;  // col-tile 0..15

  // ---- map bt -> (expert e, row0, rows) ----
  int sizes[NEXP];
#pragma unroll
  for (int i = 0; i < NEXP; ++i) sizes[i] = ms[i];
  int e = 0, row0 = 0, rows = 0, acc_t = 0, start = 0;
  bool found = false;
#pragma unroll
  for (int i = 0; i < NEXP; ++i) {
    int nt = (sizes[i] + BM - 1) >> 7;
    if (!found && bt < acc_t + nt) {
      found = true; e = i;
      int tt = bt - acc_t;
      row0 = start + tt * BM;
      rows = minI(sizes[i] - tt * BM, BM);
    }
    acc_t += nt; start += sizes[i];
  }
  if (!found) return;

  const int tid = threadIdx.x;
  const int lane = tid & 63;
  const int wave = tid >> 6;
  const int wr = wave >> 1, wc = wave & 1;  // 2x2 waves, 64x64 out each
  const int col0 = ntile * BN;

  // ---- staging: 4 units of 1KB/wave per tile (A rows w*32..+16, +16; B same)
  // per gload16: 64 lanes = 16 rows (lane>>2) x 4 phys chunks (lane&3);
  // logical chunk = (lane&3) ^ ((row>>1)&3) = (lane&3) ^ ((lane>>3)&3).
  const int rwh = wave * 32 + (lane >> 2);
  const int colel = (((lane & 3) ^ ((lane >> 3) & 3)) << 3);
  const __hip_bfloat16* aS0 = xb + (size_t)minI(row0 + rwh, M_TOTAL - 1) * KDIM + colel;
  const __hip_bfloat16* aS1 = xb + (size_t)minI(row0 + rwh + 16, M_TOTAL - 1) * KDIM + colel;
  const __hip_bfloat16* wbase = wb + (size_t)e * NDIM * KDIM;
  const __hip_bfloat16* bS0 = wbase + (size_t)(col0 + rwh) * KDIM + colel;
  const __hip_bfloat16* bS1 = wbase + (size_t)(col0 + rwh + 16) * KDIM + colel;

  // ---- fragment read byte offsets (within a buffer), swizzled ----
  const int fr = lane & 15, fc = lane >> 4;
  int offA[4], offB[4];
#pragma unroll
  for (int mt = 0; mt < 4; ++mt) {
    int r = wr * 64 + mt * 16 + fr;
    offA[mt] = r * 64 + ((fc ^ ((r >> 1) & 3)) << 4);
  }
#pragma unroll
  for (int nt = 0; nt < 4; ++nt) {
    int r = wc * 64 + nt * 16 + fr;
    offB[nt] = 8192 + r * 64 + ((fc ^ ((r >> 1) & 3)) << 4);
  }

  f32x4 acc[4][4];
  const f32x4 zero = {0.f, 0.f, 0.f, 0.f};
#pragma unroll
  for (int i = 0; i < 4; ++i)
#pragma unroll
    for (int j = 0; j < 4; ++j) acc[i][j] = zero;

#define ST4(BI, T) { char* b_ = lds + (BI) * BUFB + wave * 2048; \
    gload16(aS0 + (size_t)(T) * BK, b_); \
    gload16(aS1 + (size_t)(T) * BK, b_ + 1024); \
    gload16(bS0 + (size_t)(T) * BK, b_ + 8192); \
    gload16(bS1 + (size_t)(T) * BK, b_ + 9216); }
#define VM4 "vmcnt(4)"
#define VM0 "vmcnt(0)"

#define TILE(T, BI, DOST, VM) { \
    asm volatile("s_waitcnt " VM); \
    __builtin_amdgcn_s_barrier(); \
    const char* bb_ = lds + (BI) * BUFB; \
    bf16x8 af[4], bv[4]; \
    _Pragma("unroll") for (int mt = 0; mt < 4; ++mt) \
      af[mt] = *(const bf16x8*)(bb_ + offA[mt]); \
    _Pragma("unroll") for (int nt = 0; nt < 4; ++nt) \
      bv[nt] = *(const bf16x8*)(bb_ + offB[nt]); \
    if (DOST) ST4(((T) + 2) % 3, (T) + 2); \
    __builtin_amdgcn_s_setprio(1); \
    _Pragma("unroll") for (int nt = 0; nt < 4; ++nt) \
      _Pragma("unroll") for (int mt = 0; mt < 4; ++mt) \
        acc[mt][nt] = __builtin_amdgcn_mfma_f32_16x16x32_bf16( \
            af[mt], bv[nt], acc[mt][nt], 0, 0, 0); \
    __builtin_amdgcn_s_setprio(0); \
  }

  // prologue: tiles 0,1 in flight (8 loads/thread)
  ST4(0, 0)
  ST4(1, 1)

  for (int i = 0; i < 20; ++i) {
    const int t = 3 * i;
    TILE(t,     0, true, VM4)
    TILE(t + 1, 1, true, VM4)
    TILE(t + 2, 2, true, VM4)
  }
  TILE(60, 0, true,  VM4)   // stages 62 -> buf2
  TILE(61, 1, true,  VM4)   // stages 63 -> buf0
  TILE(62, 2, false, VM4)   // retires 62's units
  TILE(63, 0, false, VM0)   // drain 63's units

#undef TILE
#undef VM0
#undef VM4
#undef ST4

  // ---- epilogue: C/D layout col=lane&15, row=(lane>>4)*4+j ----
  const int er = (lane >> 4) * 4;
#pragma unroll
  for (int mt = 0; mt < 4; ++mt) {
#pragma unroll
    for (int j = 0; j < 4; ++j) {
      int r = wr * 64 + mt * 16 + er + j;
      if (r < rows) {
        float* op = out + (size_t)(row0 + r) * NDIM + col0 + wc * 64 + (lane & 15);
#pragma unroll
        for (int nt = 0; nt < 4; ++nt) op[nt * 16] = acc[mt][nt][j];
      }
    }
  }
}

// ---------------- fallback: direct fp32, reg-staged ----------------
__global__ __launch_bounds__(256) void moe_gemm_f32(
    const float* __restrict__ x, const float* __restrict__ w,
    const int* __restrict__ ms, float* __restrict__ out) {
  __shared__ __align__(16) char As[128 * 64 * 2];
  __shared__ __align__(16) char Bs[128 * 64 * 2];
  int sizes[NEXP];
#pragma unroll
  for (int i = 0; i < NEXP; ++i) sizes[i] = ms[i];
  const int bt = blockIdx.y;
  int e = 0, row0 = 0, rows = 0, acc_t = 0, start = 0;
  bool found = false;
#pragma unroll
  for (int i = 0; i < NEXP; ++i) {
    int nt = (sizes[i] + 127) >> 7;
    if (!found && bt < acc_t + nt) {
      found = true; e = i;
      int tt = bt - acc_t;
      row0 = start + tt * 128;
      rows = minI(sizes[i] - tt * 128, 128);
    }
    acc_t += nt; start += sizes[i];
  }
  if (!found) return;
  const int tid = threadIdx.x;
  const int lane = tid & 63;
  const int wave = tid >> 6;
  const int wm = wave >> 1, wn = wave & 1;
  const int col0 = blockIdx.x * 128;
  const float* wbase = w + (size_t)e * (size_t)NDIM * KDIM;
  const int sr = tid >> 1;
  const int sh = tid & 1;
  const float* aptr = x + (size_t)(row0 + sr) * KDIM + sh * 32;
  const float* bptr = wbase + (size_t)(col0 + sr) * KDIM + sh * 32;
  const bool aval = (sr < rows);
  f32x4 acc[4][4];
  const f32x4 zero = {0.f, 0.f, 0.f, 0.f};
#pragma unroll
  for (int i = 0; i < 4; ++i)
#pragma unroll
    for (int j = 0; j < 4; ++j) acc[i][j] = zero;
  for (int kb = 0; kb < KDIM / 64; ++kb) {
    {
      float4 v[8];
      if (aval) {
        const float4* p = (const float4*)(aptr + kb * 64);
#pragma unroll
        for (int j = 0; j < 8; ++j) v[j] = p[j];
      } else {
#pragma unroll
        for (int j = 0; j < 8; ++j) v[j] = make_float4(0.f, 0.f, 0.f, 0.f);
      }
#pragma unroll
      for (int j = 0; j < 4; ++j) {
        bf16x8 c = cvt8(v[2 * j], v[2 * j + 1]);
        int chunk = (sh * 4 + j) ^ (sr & 7);
        *(bf16x8*)(As + sr * 128 + chunk * 16) = c;
      }
    }
    {
      const float4* p = (const float4*)(bptr + kb * 64);
      float4 u[8];
#pragma unroll
      for (int j = 0; j < 8; ++j) u[j] = p[j];
#pragma unroll
      for (int j = 0; j < 4; ++j) {
        bf16x8 c = cvt8(u[2 * j], u[2 * j + 1]);
        int chunk = (sh * 4 + j) ^ (sr & 7);
        *(bf16x8*)(Bs + sr * 128 + chunk * 16) = c;
      }
    }
    __syncthreads();
#pragma unroll
    for (int ks = 0; ks < 2; ++ks) {
      bf16x8 afr[4], bfv[4];
#pragma unroll
      for (int mt = 0; mt < 4; ++mt) {
        int r = wm * 64 + mt * 16 + (lane & 15);
        int chunk = (ks * 4 + (lane >> 4)) ^ (r & 7);
        afr[mt] = *(const bf16x8*)(As + r * 128 + chunk * 16);
      }
#pragma unroll
      for (int nt = 0; nt < 4; ++nt) {
        int r = wn * 64 + nt * 16 + (lane & 15);
        int chunk = (ks * 4 + (lane >> 4)) ^ (r & 7);
        bfv[nt] = *(const bf16x8*)(Bs + r * 128 + chunk * 16);
      }
#pragma unroll
      for (int mt = 0; mt < 4; ++mt)
#pragma unroll
        for (int nt = 0; nt < 4; ++nt)
          acc[mt][nt] = __builtin_amdgcn_mfma_f32_16x16x32_bf16(
              afr[mt], bfv[nt], acc[mt][nt], 0, 0, 0);
    }
    __syncthreads();
  }
#pragma unroll
  for (int mt = 0; mt < 4; ++mt) {
#pragma unroll
    for (int j = 0; j < 4; ++j) {
      int r = wm * 64 + mt * 16 + (lane >> 4) * 4 + j;
      if (r < rows) {
        float* op = out + (size_t)(row0 + r) * NDIM + col0 + wn * 64 + (lane & 15);
#pragma unroll
        for (int nt = 0; nt < 4; ++nt) op[nt * 16] = acc[mt][nt][j];
      }
    }
  }
}

extern "C" void kernel_launch(void* const* d_in, const int* in_sizes, int n_in,
                              void* d_out, int out_size, void* d_ws, size_t ws_size,
                              hipStream_t stream) {
  const float* x = (const float*)d_in[0];
  const float* w = (const float*)d_in[1];
  const int* ms = (const int*)d_in[2];
  float* out = (float*)d_out;
  const size_t nx = (size_t)M_TOTAL * KDIM;
  const size_t nw = (size_t)NEXP * NDIM * KDIM;
  const size_t need = (nx + nw) * sizeof(__hip_bfloat16);
  if (ws_size >= need) {
    __hip_bfloat16* xb = (__hip_bfloat16*)d_ws;
    __hip_bfloat16* wb = xb + nx;
    cvt_both<<<2048, 256, 0, stream>>>(x, w, (bf16x8*)xb, (bf16x8*)wb);
    moe_gemm_cr<<<dim3(NWG), dim3(256), 0, stream>>>(xb, wb, ms, out);
  } else {
    moe_gemm_f32<<<dim3(16, 135), dim3(256), 0, stream>>>(x, w, ms, out);
  }
}

// Round 13
// 271.229 us; speedup vs baseline: 1.0332x; 1.0332x over previous
//
#include <hip/hip_runtime.h>
#include <hip/hip_bf16.h>

#define M_TOTAL 16384
#define KDIM 2048
#define NDIM 2048
#define NEXP 8
#define BM 256
#define BN 128
#define BK 32
#define RT_MAX 71           // 16384/256 + 7 boundary extras
#define CT 16               // 2048/128 col tiles
#define NWG (RT_MAX * CT)   // 1136 = 8 * 142
#define BUFB 24576          // (256+128) rows x 64B per K-tile buffer

typedef __attribute__((ext_vector_type(8))) __bf16 bf16x8;
typedef __attribute__((ext_vector_type(4))) float f32x4;

__device__ inline int minI(int a, int b) { return a < b ? a : b; }

__device__ inline bf16x8 cvt8(float4 a, float4 b) {
  bf16x8 r;
  r[0] = (__bf16)a.x; r[1] = (__bf16)a.y; r[2] = (__bf16)a.z; r[3] = (__bf16)a.w;
  r[4] = (__bf16)b.x; r[5] = (__bf16)b.y; r[6] = (__bf16)b.z; r[7] = (__bf16)b.w;
  return r;
}

__device__ inline void gload16(const void* g, void* l) {
  __builtin_amdgcn_global_load_lds(
      (const __attribute__((address_space(1))) void*)g,
      (__attribute__((address_space(3))) void*)l, 16, 0, 0);
}

// ---------------- fp32 -> bf16 conversion (x then W) ----------------
__global__ __launch_bounds__(256) void cvt_both(
    const float* __restrict__ x, const float* __restrict__ w,
    bf16x8* __restrict__ xb, bf16x8* __restrict__ wb) {
  const int NX = (M_TOTAL * KDIM) / 8;
  const int NW = (NEXP * NDIM * KDIM) / 8;
  const int stride = gridDim.x * blockDim.x;
  for (int i = blockIdx.x * blockDim.x + threadIdx.x; i < NX + NW; i += stride) {
    const float4* src = (i < NX) ? ((const float4*)x + (size_t)i * 2)
                                 : ((const float4*)w + (size_t)(i - NX) * 2);
    float4 a = src[0], b = src[1];
    bf16x8 c = cvt8(a, b);
    if (i < NX) xb[i] = c; else wb[i - NX] = c;
  }
}

// ---------------- grouped GEMM: 256x128 tile, BK=32, 2 LDS buffers (48 KB),
// 8 waves (4M x 2N) of 64x64, VGPR<=128 (__launch_bounds__(512,4)) -> >=2
// blocks CO-RESIDENT per CU.
// Post-R12 accounting: intensity 0.0234 (256^2) forces 1 block/CU (acc=128
// VGPR/lane) -> no cross-block overlap -> the 29-35% MfmaUtil wall seen in
// R4-R11. This geometry (acc=64) is the only one that both co-resides and
// keeps intensity acceptable (0.0313 B/FLOP -> 65% ideal duty). R5 tried it
// but with memory-clobbered waits (every counted vmcnt compiled to a full
// vmcnt0+lgkm0 drain -- the R9-discovered SIInsertWaitcnts behavior) plus a
// lockstep lgkm(0) before each MFMA cluster. This version is clean:
// per tile: stage(t+1) at top -> free-running ds_reads (compiler partial
// lgkm waits) -> 16 MFMA under setprio -> clobber-free vmcnt(0) (drains
// loads issued one full tile earlier) -> ONE barrier. Co-resident blocks
// fill all stall windows (m97/m114 mechanism).
// Hazards: RAW -- reads(t) need stage(t) (issued top of t-1): vmcnt(0)+
// barrier at end of t-1 publish it. WAR -- stage(t+1)->buf[(t+1)&1] whose
// readers (tile t-1) completed their ds_reads before passing barrier(t-1),
// which precedes this issue. Swizzle (0 conflicts since R3): phys chunk =
// c ^ ((row>>1)&3) via pre-swizzled per-lane global column; LDS dest linear.
__global__ __launch_bounds__(512, 4) void moe_gemm_co(
    const __hip_bfloat16* __restrict__ xb, const __hip_bfloat16* __restrict__ wb,
    const int* __restrict__ ms, float* __restrict__ out) {
  __shared__ __align__(16) char lds[2 * BUFB];

  // bijective XCD swizzle (NWG = 1136 = 8*142); col-tiles contiguous per XCD
  const int orig = blockIdx.x;
  const int wg = (orig & 7) * (NWG / 8) + (orig >> 3);
  const int bt = wg >> 4;     // row-tile 0..70
  const int ntile = wg & 15;  // col-tile 0..15

  // ---- map bt -> (expert e, row0, rows) ----
  int sizes[NEXP];
#pragma unroll
  for (int i = 0; i < NEXP; ++i) sizes[i] = ms[i];
  int e = 0, row0 = 0, rows = 0, acc_t = 0, start = 0;
  bool found = false;
#pragma unroll
  for (int i = 0; i < NEXP; ++i) {
    int nt = (sizes[i] + BM - 1) >> 8;
    if (!found && bt < acc_t + nt) {
      found = true; e = i;
      int tt = bt - acc_t;
      row0 = start + tt * BM;
      rows = minI(sizes[i] - tt * BM, BM);
    }
    acc_t += nt; start += sizes[i];
  }
  if (!found) return;

  const int tid = threadIdx.x;
  const int lane = tid & 63;
  const int wave = tid >> 6;
  const int wr = wave >> 1, wc = wave & 1;  // 4M x 2N waves, 64x64 out each
  const int col0 = ntile * BN;

  // ---- staging: 3 units of 8KB (A rows 0-127, A rows 128-255, B rows 0-127)
  // thread -> row rwh = wave*16 + lane>>2 (128 rows/unit), phys chunk lane&3;
  // logical chunk = (lane&3) ^ ((rwh>>1)&3) = (lane&3) ^ ((lane>>3)&3).
  const int rwh = wave * 16 + (lane >> 2);
  const int colel = (((lane & 3) ^ ((lane >> 3) & 3)) << 3);
  const __hip_bfloat16* aS0 = xb + (size_t)minI(row0 + rwh, M_TOTAL - 1) * KDIM + colel;
  const __hip_bfloat16* aS1 = xb + (size_t)minI(row0 + 128 + rwh, M_TOTAL - 1) * KDIM + colel;
  const __hip_bfloat16* wbase = wb + (size_t)e * NDIM * KDIM;
  const __hip_bfloat16* bS = wbase + (size_t)(col0 + rwh) * KDIM + colel;

  // ---- fragment read byte offsets (within a buffer), swizzled ----
  const int fr = lane & 15, fc = lane >> 4;
  int offA[4], offB[4];
#pragma unroll
  for (int mt = 0; mt < 4; ++mt) {
    int r = wr * 64 + mt * 16 + fr;
    offA[mt] = r * 64 + ((fc ^ ((r >> 1) & 3)) << 4);
  }
#pragma unroll
  for (int nt = 0; nt < 4; ++nt) {
    int r = wc * 64 + nt * 16 + fr;
    offB[nt] = 16384 + r * 64 + ((fc ^ ((r >> 1) & 3)) << 4);
  }

  f32x4 acc[4][4];
  const f32x4 zero = {0.f, 0.f, 0.f, 0.f};
#pragma unroll
  for (int i = 0; i < 4; ++i)
#pragma unroll
    for (int j = 0; j < 4; ++j) acc[i][j] = zero;

#define ST3(BI, T) { char* b_ = lds + (BI) * BUFB + wave * 1024; \
    gload16(aS0 + (size_t)(T) * BK, b_); \
    gload16(aS1 + (size_t)(T) * BK, b_ + 8192); \
    gload16(bS + (size_t)(T) * BK, b_ + 16384); }

// Tile T: stage T+1 first (max latency cover), free-run reads+MFMA, then
// drain+publish. Clobber-free waits (counted semantics preserved).
#define TILE(T, BR, BI, DOST) { \
    if (DOST) ST3(BI, (T) + 1); \
    const char* bb_ = lds + (BR) * BUFB; \
    bf16x8 af[4], bv[4]; \
    _Pragma("unroll") for (int mt = 0; mt < 4; ++mt) \
      af[mt] = *(const bf16x8*)(bb_ + offA[mt]); \
    _Pragma("unroll") for (int nt = 0; nt < 4; ++nt) \
      bv[nt] = *(const bf16x8*)(bb_ + offB[nt]); \
    __builtin_amdgcn_s_setprio(1); \
    _Pragma("unroll") for (int nt = 0; nt < 4; ++nt) \
      _Pragma("unroll") for (int mt = 0; mt < 4; ++mt) \
        acc[mt][nt] = __builtin_amdgcn_mfma_f32_16x16x32_bf16( \
            af[mt], bv[nt], acc[mt][nt], 0, 0, 0); \
    __builtin_amdgcn_s_setprio(0); \
    asm volatile("s_waitcnt vmcnt(0)"); \
    __builtin_amdgcn_s_barrier(); \
  }

  // prologue: stage tile 0, publish
  ST3(0, 0)
  asm volatile("s_waitcnt vmcnt(0)");
  __builtin_amdgcn_s_barrier();

  for (int i = 0; i < 31; ++i) {
    TILE(2 * i,     0, 1, true)
    TILE(2 * i + 1, 1, 0, true)
  }
  TILE(62, 0, 1, true)
  TILE(63, 1, 0, false)

#undef TILE
#undef ST3

  // ---- epilogue: C/D layout col=lane&15, row=(lane>>4)*4+j ----
  const int er = (lane >> 4) * 4;
#pragma unroll
  for (int mt = 0; mt < 4; ++mt) {
#pragma unroll
    for (int j = 0; j < 4; ++j) {
      int r = wr * 64 + mt * 16 + er + j;
      if (r < rows) {
        float* op = out + (size_t)(row0 + r) * NDIM + col0 + wc * 64 + (lane & 15);
#pragma unroll
        for (int nt = 0; nt < 4; ++nt) op[nt * 16] = acc[mt][nt][j];
      }
    }
  }
}

// ---------------- fallback: direct fp32, reg-staged ----------------
__global__ __launch_bounds__(256) void moe_gemm_f32(
    const float* __restrict__ x, const float* __restrict__ w,
    const int* __restrict__ ms, float* __restrict__ out) {
  __shared__ __align__(16) char As[128 * 64 * 2];
  __shared__ __align__(16) char Bs[128 * 64 * 2];
  int sizes[NEXP];
#pragma unroll
  for (int i = 0; i < NEXP; ++i) sizes[i] = ms[i];
  const int bt = blockIdx.y;
  int e = 0, row0 = 0, rows = 0, acc_t = 0, start = 0;
  bool found = false;
#pragma unroll
  for (int i = 0; i < NEXP; ++i) {
    int nt = (sizes[i] + 127) >> 7;
    if (!found && bt < acc_t + nt) {
      found = true; e = i;
      int tt = bt - acc_t;
      row0 = start + tt * 128;
      rows = minI(sizes[i] - tt * 128, 128);
    }
    acc_t += nt; start += sizes[i];
  }
  if (!found) return;
  const int tid = threadIdx.x;
  const int lane = tid & 63;
  const int wave = tid >> 6;
  const int wm = wave >> 1, wn = wave & 1;
  const int col0 = blockIdx.x * 128;
  const float* wbase = w + (size_t)e * (size_t)NDIM * KDIM;
  const int sr = tid >> 1;
  const int sh = tid & 1;
  const float* aptr = x + (size_t)(row0 + sr) * KDIM + sh * 32;
  const float* bptr = wbase + (size_t)(col0 + sr) * KDIM + sh * 32;
  const bool aval = (sr < rows);
  f32x4 acc[4][4];
  const f32x4 zero = {0.f, 0.f, 0.f, 0.f};
#pragma unroll
  for (int i = 0; i < 4; ++i)
#pragma unroll
    for (int j = 0; j < 4; ++j) acc[i][j] = zero;
  for (int kb = 0; kb < KDIM / 64; ++kb) {
    {
      float4 v[8];
      if (aval) {
        const float4* p = (const float4*)(aptr + kb * 64);
#pragma unroll
        for (int j = 0; j < 8; ++j) v[j] = p[j];
      } else {
#pragma unroll
        for (int j = 0; j < 8; ++j) v[j] = make_float4(0.f, 0.f, 0.f, 0.f);
      }
#pragma unroll
      for (int j = 0; j < 4; ++j) {
        bf16x8 c = cvt8(v[2 * j], v[2 * j + 1]);
        int chunk = (sh * 4 + j) ^ (sr & 7);
        *(bf16x8*)(As + sr * 128 + chunk * 16) = c;
      }
    }
    {
      const float4* p = (const float4*)(bptr + kb * 64);
      float4 u[8];
#pragma unroll
      for (int j = 0; j < 8; ++j) u[j] = p[j];
#pragma unroll
      for (int j = 0; j < 4; ++j) {
        bf16x8 c = cvt8(u[2 * j], u[2 * j + 1]);
        int chunk = (sh * 4 + j) ^ (sr & 7);
        *(bf16x8*)(Bs + sr * 128 + chunk * 16) = c;
      }
    }
    __syncthreads();
#pragma unroll
    for (int ks = 0; ks < 2; ++ks) {
      bf16x8 afr[4], bfv[4];
#pragma unroll
      for (int mt = 0; mt < 4; ++mt) {
        int r = wm * 64 + mt * 16 + (lane & 15);
        int chunk = (ks * 4 + (lane >> 4)) ^ (r & 7);
        afr[mt] = *(const bf16x8*)(As + r * 128 + chunk * 16);
      }
#pragma unroll
      for (int nt = 0; nt < 4; ++nt) {
        int r = wn * 64 + nt * 16 + (lane & 15);
        int chunk = (ks * 4 + (lane >> 4)) ^ (r & 7);
        bfv[nt] = *(const bf16x8*)(Bs + r * 128 + chunk * 16);
      }
#pragma unroll
      for (int mt = 0; mt < 4; ++mt)
#pragma unroll
        for (int nt = 0; nt < 4; ++nt)
          acc[mt][nt] = __builtin_amdgcn_mfma_f32_16x16x32_bf16(
              afr[mt], bfv[nt], acc[mt][nt], 0, 0, 0);
    }
    __syncthreads();
  }
#pragma unroll
  for (int mt = 0; mt < 4; ++mt) {
#pragma unroll
    for (int j = 0; j < 4; ++j) {
      int r = wm * 64 + mt * 16 + (lane >> 4) * 4 + j;
      if (r < rows) {
        float* op = out + (size_t)(row0 + r) * NDIM + col0 + wn * 64 + (lane & 15);
#pragma unroll
        for (int nt = 0; nt < 4; ++nt) op[nt * 16] = acc[mt][nt][j];
      }
    }
  }
}

extern "C" void kernel_launch(void* const* d_in, const int* in_sizes, int n_in,
                              void* d_out, int out_size, void* d_ws, size_t ws_size,
                              hipStream_t stream) {
  const float* x = (const float*)d_in[0];
  const float* w = (const float*)d_in[1];
  const int* ms = (const int*)d_in[2];
  float* out = (float*)d_out;
  const size_t nx = (size_t)M_TOTAL * KDIM;
  const size_t nw = (size_t)NEXP * NDIM * KDIM;
  const size_t need = (nx + nw) * sizeof(__hip_bfloat16);
  if (ws_size >= need) {
    __hip_bfloat16* xb = (__hip_bfloat16*)d_ws;
    __hip_bfloat16* wb = xb + nx;
    cvt_both<<<2048, 256, 0, stream>>>(x, w, (bf16x8*)xb, (bf16x8*)wb);
    moe_gemm_co<<<dim3(NWG), dim3(512), 0, stream>>>(xb, wb, ms, out);
  } else {
    moe_gemm_f32<<<dim3(16, 135), dim3(256), 0, stream>>>(x, w, ms, out);
  }
}

// Round 14
// 255.650 us; speedup vs baseline: 1.0961x; 1.0609x over previous
//
#include <hip/hip_runtime.h>
#include <hip/hip_bf16.h>

#define M_TOTAL 16384
#define KDIM 2048
#define NDIM 2048
#define NEXP 8
#define BM 256
#define BN 128
#define BK 32
#define RT_MAX 71           // 16384/256 + 7 boundary extras
#define CT 16               // 2048/128 col tiles
#define NWG (RT_MAX * CT)   // 1136 = 8 * 142
#define BUFB 24576          // (256+128) rows x 64B per K-tile buffer

typedef __attribute__((ext_vector_type(8))) __bf16 bf16x8;
typedef __attribute__((ext_vector_type(4))) float f32x4;

__device__ inline int minI(int a, int b) { return a < b ? a : b; }

__device__ inline bf16x8 cvt8(float4 a, float4 b) {
  bf16x8 r;
  r[0] = (__bf16)a.x; r[1] = (__bf16)a.y; r[2] = (__bf16)a.z; r[3] = (__bf16)a.w;
  r[4] = (__bf16)b.x; r[5] = (__bf16)b.y; r[6] = (__bf16)b.z; r[7] = (__bf16)b.w;
  return r;
}

__device__ inline void gload16(const void* g, void* l) {
  __builtin_amdgcn_global_load_lds(
      (const __attribute__((address_space(1))) void*)g,
      (__attribute__((address_space(3))) void*)l, 16, 0, 0);
}

// ---------------- fp32 -> bf16 conversion (x then W) ----------------
__global__ __launch_bounds__(256) void cvt_both(
    const float* __restrict__ x, const float* __restrict__ w,
    bf16x8* __restrict__ xb, bf16x8* __restrict__ wb) {
  const int NX = (M_TOTAL * KDIM) / 8;
  const int NW = (NEXP * NDIM * KDIM) / 8;
  const int stride = gridDim.x * blockDim.x;
  for (int i = blockIdx.x * blockDim.x + threadIdx.x; i < NX + NW; i += stride) {
    const float4* src = (i < NX) ? ((const float4*)x + (size_t)i * 2)
                                 : ((const float4*)w + (size_t)(i - NX) * 2);
    float4 a = src[0], b = src[1];
    bf16x8 c = cvt8(a, b);
    if (i < NX) xb[i] = c; else wb[i - NX] = c;
  }
}

// ---------------- grouped GEMM: 256x128 tile, BK=32, THREE LDS buffers
// (72 KB x 2 blocks = 144 KB/CU), 8 waves (4M x 2N) of 64x64, VGPR<=128 ->
// TWO blocks co-resident per CU (R13 confirmed: occupancy 34%).
// R13's flaw: stage-1-ahead + vmcnt(0) per tile = full drain of staging loads
// issued only ~1300 cyc earlier with 600-900 cyc L2-miss/L3 latency -> ~2300
// cyc stall per tile (measured 3600 cyc/tile vs 1270 pipe work). This round:
// stage TWO ahead, counted clobber-free vmcnt(3) at tile end -- retires tile
// t+1's 3 units (issued 2 full tiles ~2600+ cyc earlier, latency fully
// covered), leaves tile t+2's units in flight. Counted-vmcnt + co-residency
// combined for the first time (R4-R11 counted were all 1 block/CU; R5/R13
// co-resident were full-drain).
// Hazards: RAW -- reads(t) from buf[t%3]: staged top of t-2, retired by
// vmcnt(3) at end of t-1, published by barrier(t-1). WAR -- stage(t+2) ->
// buf[(t+2)%3], read during tile t-1: those ds_reads completed before their
// MFMAs, which completed before each wave passed barrier(t-1), which precedes
// this issue. Swizzle (0 conflicts since R3): phys chunk = c ^ ((row>>1)&3)
// via pre-swizzled per-lane global source column; LDS dest stays linear.
__global__ __launch_bounds__(512, 4) void moe_gemm_c3(
    const __hip_bfloat16* __restrict__ xb, const __hip_bfloat16* __restrict__ wb,
    const int* __restrict__ ms, float* __restrict__ out) {
  __shared__ __align__(16) char lds[3 * BUFB];

  // bijective XCD swizzle (NWG = 1136 = 8*142)
  const int orig = blockIdx.x;
  const int wg = (orig & 7) * (NWG / 8) + (orig >> 3);
  const int bt = wg >> 4;     // row-tile 0..70
  const int ntile = wg & 15;  // col-tile 0..15

  // ---- map bt -> (expert e, row0, rows) ----
  int sizes[NEXP];
#pragma unroll
  for (int i = 0; i < NEXP; ++i) sizes[i] = ms[i];
  int e = 0, row0 = 0, rows = 0, acc_t = 0, start = 0;
  bool found = false;
#pragma unroll
  for (int i = 0; i < NEXP; ++i) {
    int nt = (sizes[i] + BM - 1) >> 8;
    if (!found && bt < acc_t + nt) {
      found = true; e = i;
      int tt = bt - acc_t;
      row0 = start + tt * BM;
      rows = minI(sizes[i] - tt * BM, BM);
    }
    acc_t += nt; start += sizes[i];
  }
  if (!found) return;

  const int tid = threadIdx.x;
  const int lane = tid & 63;
  const int wave = tid >> 6;
  const int wr = wave >> 1, wc = wave & 1;  // 4M x 2N waves, 64x64 out each
  const int col0 = ntile * BN;

  // ---- staging: 3 units of 8KB (A rows 0-127, A rows 128-255, B rows 0-127)
  // thread -> row rwh = wave*16 + lane>>2, phys chunk lane&3;
  // logical chunk = (lane&3) ^ ((rwh>>1)&3) = (lane&3) ^ ((lane>>3)&3).
  const int rwh = wave * 16 + (lane >> 2);
  const int colel = (((lane & 3) ^ ((lane >> 3) & 3)) << 3);
  const __hip_bfloat16* aS0 = xb + (size_t)minI(row0 + rwh, M_TOTAL - 1) * KDIM + colel;
  const __hip_bfloat16* aS1 = xb + (size_t)minI(row0 + 128 + rwh, M_TOTAL - 1) * KDIM + colel;
  const __hip_bfloat16* wbase = wb + (size_t)e * NDIM * KDIM;
  const __hip_bfloat16* bS = wbase + (size_t)(col0 + rwh) * KDIM + colel;

  // ---- fragment read byte offsets (within a buffer), swizzled ----
  const int fr = lane & 15, fc = lane >> 4;
  int offA[4], offB[4];
#pragma unroll
  for (int mt = 0; mt < 4; ++mt) {
    int r = wr * 64 + mt * 16 + fr;
    offA[mt] = r * 64 + ((fc ^ ((r >> 1) & 3)) << 4);
  }
#pragma unroll
  for (int nt = 0; nt < 4; ++nt) {
    int r = wc * 64 + nt * 16 + fr;
    offB[nt] = 16384 + r * 64 + ((fc ^ ((r >> 1) & 3)) << 4);
  }

  f32x4 acc[4][4];
  const f32x4 zero = {0.f, 0.f, 0.f, 0.f};
#pragma unroll
  for (int i = 0; i < 4; ++i)
#pragma unroll
    for (int j = 0; j < 4; ++j) acc[i][j] = zero;

#define ST3(BI, T) { char* b_ = lds + (BI) * BUFB + wave * 1024; \
    gload16(aS0 + (size_t)(T) * BK, b_); \
    gload16(aS1 + (size_t)(T) * BK, b_ + 8192); \
    gload16(bS + (size_t)(T) * BK, b_ + 16384); }

// Tile T: stage T+2 first (2-tile latency cover), free-run reads + MFMA,
// then counted clobber-free vmcnt + barrier (publishes buf[(T+1)%3]).
#define TILE(T, BR, BI2, DOST, VM) { \
    if (DOST) ST3(BI2, (T) + 2); \
    const char* bb_ = lds + (BR) * BUFB; \
    bf16x8 af[4], bv[4]; \
    _Pragma("unroll") for (int mt = 0; mt < 4; ++mt) \
      af[mt] = *(const bf16x8*)(bb_ + offA[mt]); \
    _Pragma("unroll") for (int nt = 0; nt < 4; ++nt) \
      bv[nt] = *(const bf16x8*)(bb_ + offB[nt]); \
    __builtin_amdgcn_s_setprio(1); \
    _Pragma("unroll") for (int nt = 0; nt < 4; ++nt) \
      _Pragma("unroll") for (int mt = 0; mt < 4; ++mt) \
        acc[mt][nt] = __builtin_amdgcn_mfma_f32_16x16x32_bf16( \
            af[mt], bv[nt], acc[mt][nt], 0, 0, 0); \
    __builtin_amdgcn_s_setprio(0); \
    asm volatile("s_waitcnt " VM); \
    __builtin_amdgcn_s_barrier(); \
  }

  // prologue: stage tiles 0,1 (6 units); vmcnt(3) retires tile 0's units,
  // leaves tile 1's in flight; barrier publishes buf0.
  ST3(0, 0)
  ST3(1, 1)
  asm volatile("s_waitcnt vmcnt(3)");
  __builtin_amdgcn_s_barrier();

  for (int i = 0; i < 20; ++i) {
    const int t = 3 * i;
    TILE(t,     0, 2, true, "vmcnt(3)")
    TILE(t + 1, 1, 0, true, "vmcnt(3)")
    TILE(t + 2, 2, 1, true, "vmcnt(3)")
  }
  TILE(60, 0, 2, true,  "vmcnt(3)")   // stages 62 -> buf2
  TILE(61, 1, 0, true,  "vmcnt(3)")   // stages 63 -> buf0; retires 62's units
  TILE(62, 2, 0, false, "vmcnt(0)")   // drain: 63's units land
  TILE(63, 0, 0, false, "vmcnt(0)")   // no outstanding; wait is free

#undef TILE
#undef ST3

  // ---- epilogue: C/D layout col=lane&15, row=(lane>>4)*4+j ----
  const int er = (lane >> 4) * 4;
#pragma unroll
  for (int mt = 0; mt < 4; ++mt) {
#pragma unroll
    for (int j = 0; j < 4; ++j) {
      int r = wr * 64 + mt * 16 + er + j;
      if (r < rows) {
        float* op = out + (size_t)(row0 + r) * NDIM + col0 + wc * 64 + (lane & 15);
#pragma unroll
        for (int nt = 0; nt < 4; ++nt) op[nt * 16] = acc[mt][nt][j];
      }
    }
  }
}

// ---------------- fallback: direct fp32, reg-staged ----------------
__global__ __launch_bounds__(256) void moe_gemm_f32(
    const float* __restrict__ x, const float* __restrict__ w,
    const int* __restrict__ ms, float* __restrict__ out) {
  __shared__ __align__(16) char As[128 * 64 * 2];
  __shared__ __align__(16) char Bs[128 * 64 * 2];
  int sizes[NEXP];
#pragma unroll
  for (int i = 0; i < NEXP; ++i) sizes[i] = ms[i];
  const int bt = blockIdx.y;
  int e = 0, row0 = 0, rows = 0, acc_t = 0, start = 0;
  bool found = false;
#pragma unroll
  for (int i = 0; i < NEXP; ++i) {
    int nt = (sizes[i] + 127) >> 7;
    if (!found && bt < acc_t + nt) {
      found = true; e = i;
      int tt = bt - acc_t;
      row0 = start + tt * 128;
      rows = minI(sizes[i] - tt * 128, 128);
    }
    acc_t += nt; start += sizes[i];
  }
  if (!found) return;
  const int tid = threadIdx.x;
  const int lane = tid & 63;
  const int wave = tid >> 6;
  const int wm = wave >> 1, wn = wave & 1;
  const int col0 = blockIdx.x * 128;
  const float* wbase = w + (size_t)e * (size_t)NDIM * KDIM;
  const int sr = tid >> 1;
  const int sh = tid & 1;
  const float* aptr = x + (size_t)(row0 + sr) * KDIM + sh * 32;
  const float* bptr = wbase + (size_t)(col0 + sr) * KDIM + sh * 32;
  const bool aval = (sr < rows);
  f32x4 acc[4][4];
  const f32x4 zero = {0.f, 0.f, 0.f, 0.f};
#pragma unroll
  for (int i = 0; i < 4; ++i)
#pragma unroll
    for (int j = 0; j < 4; ++j) acc[i][j] = zero;
  for (int kb = 0; kb < KDIM / 64; ++kb) {
    {
      float4 v[8];
      if (aval) {
        const float4* p = (const float4*)(aptr + kb * 64);
#pragma unroll
        for (int j = 0; j < 8; ++j) v[j] = p[j];
      } else {
#pragma unroll
        for (int j = 0; j < 8; ++j) v[j] = make_float4(0.f, 0.f, 0.f, 0.f);
      }
#pragma unroll
      for (int j = 0; j < 4; ++j) {
        bf16x8 c = cvt8(v[2 * j], v[2 * j + 1]);
        int chunk = (sh * 4 + j) ^ (sr & 7);
        *(bf16x8*)(As + sr * 128 + chunk * 16) = c;
      }
    }
    {
      const float4* p = (const float4*)(bptr + kb * 64);
      float4 u[8];
#pragma unroll
      for (int j = 0; j < 8; ++j) u[j] = p[j];
#pragma unroll
      for (int j = 0; j < 4; ++j) {
        bf16x8 c = cvt8(u[2 * j], u[2 * j + 1]);
        int chunk = (sh * 4 + j) ^ (sr & 7);
        *(bf16x8*)(Bs + sr * 128 + chunk * 16) = c;
      }
    }
    __syncthreads();
#pragma unroll
    for (int ks = 0; ks < 2; ++ks) {
      bf16x8 afr[4], bfv[4];
#pragma unroll
      for (int mt = 0; mt < 4; ++mt) {
        int r = wm * 64 + mt * 16 + (lane & 15);
        int chunk = (ks * 4 + (lane >> 4)) ^ (r & 7);
        afr[mt] = *(const bf16x8*)(As + r * 128 + chunk * 16);
      }
#pragma unroll
      for (int nt = 0; nt < 4; ++nt) {
        int r = wn * 64 + nt * 16 + (lane & 15);
        int chunk = (ks * 4 + (lane >> 4)) ^ (r & 7);
        bfv[nt] = *(const bf16x8*)(Bs + r * 128 + chunk * 16);
      }
#pragma unroll
      for (int mt = 0; mt < 4; ++mt)
#pragma unroll
        for (int nt = 0; nt < 4; ++nt)
          acc[mt][nt] = __builtin_amdgcn_mfma_f32_16x16x32_bf16(
              afr[mt], bfv[nt], acc[mt][nt], 0, 0, 0);
    }
    __syncthreads();
  }
#pragma unroll
  for (int mt = 0; mt < 4; ++mt) {
#pragma unroll
    for (int j = 0; j < 4; ++j) {
      int r = wm * 64 + mt * 16 + (lane >> 4) * 4 + j;
      if (r < rows) {
        float* op = out + (size_t)(row0 + r) * NDIM + col0 + wn * 64 + (lane & 15);
#pragma unroll
        for (int nt = 0; nt < 4; ++nt) op[nt * 16] = acc[mt][nt][j];
      }
    }
  }
}

extern "C" void kernel_launch(void* const* d_in, const int* in_sizes, int n_in,
                              void* d_out, int out_size, void* d_ws, size_t ws_size,
                              hipStream_t stream) {
  const float* x = (const float*)d_in[0];
  const float* w = (const float*)d_in[1];
  const int* ms = (const int*)d_in[2];
  float* out = (float*)d_out;
  const size_t nx = (size_t)M_TOTAL * KDIM;
  const size_t nw = (size_t)NEXP * NDIM * KDIM;
  const size_t need = (nx + nw) * sizeof(__hip_bfloat16);
  if (ws_size >= need) {
    __hip_bfloat16* xb = (__hip_bfloat16*)d_ws;
    __hip_bfloat16* wb = xb + nx;
    cvt_both<<<2048, 256, 0, stream>>>(x, w, (bf16x8*)xb, (bf16x8*)wb);
    moe_gemm_c3<<<dim3(NWG), dim3(512), 0, stream>>>(xb, wb, ms, out);
  } else {
    moe_gemm_f32<<<dim3(16, 135), dim3(256), 0, stream>>>(x, w, ms, out);
  }
}